// Round 8
// baseline (484.143 us; speedup 1.0000x reference)
//
#include <hip/hip_runtime.h>
#include <hip/hip_bf16.h>

// GCN encoder: z = relu(A @ relu(A @ (x@W1) + b1) @ W2 + b2)
// R13: contiguous-burst A-slab GEMMs. R12 post-mortem: 5 schedules (serial,
// dbuf, counted-vmcnt, hybrid) ALL land 60-70us @ ~2TB/s -> scheduling was
// never the constraint; the shared factor is the A access pattern (128B
// chunks of 16 interleaved 2KB-strided rows per wave => ~35K concurrent
// short streams chip-wide, DRAM row-buffer thrash caps service rate).
// Now: each wave streams its 16 A-rows CONTIGUOUSLY (row = one 2KB wave
// load; wave slab = 32KB contiguous; block slab = 128KB contiguous) into a
// full-K LDS slab (64KB, XOR-swizzled, wave-private quadrants -> ZERO
// barriers in gemm1). K-loop: af from LDS; B direct from L2 with 1-phase
// register dbuf (R10-verified addressing, now actually prefetched).
// launch_bounds(256,2): LDS 64KB -> 2 blocks/CU; block2's A-stream overlaps
// block1's K-loop. gemm2: same slab idea via gll16 (+1 syncthreads).

typedef __attribute__((ext_vector_type(8))) short bf16x8;
typedef __attribute__((ext_vector_type(4))) float f32x4;

#define NN 50000
#define NE 800000
#define NF 512
#define NH 256
#define NL 128
#define NB ((NN + 255) / 256)

static __device__ __forceinline__ unsigned short f2bf(float f) {
  union { float f; unsigned int u; } v; v.f = f;
  unsigned int r = v.u + 0x7fffu + ((v.u >> 16) & 1u);   // RNE
  return (unsigned short)(r >> 16);
}
static __device__ __forceinline__ float bf2f(unsigned short u) {
  union { unsigned int u; float f; } v; v.u = (unsigned int)u << 16;
  return v.f;
}

// HW packed f32->bf16 (RNE), 2 elems / instruction (no builtin on gfx950).
static __device__ __forceinline__ unsigned int pkbf(float lo, float hi) {
  unsigned int r;
  asm("v_cvt_pk_bf16_f32 %0, %1, %2" : "=v"(r) : "v"(lo), "v"(hi));
  return r;
}
static __device__ __forceinline__ uint4 pk8(float4 a, float4 b) {
  uint4 o;
  o.x = pkbf(a.x, a.y); o.y = pkbf(a.z, a.w);
  o.z = pkbf(b.x, b.y); o.w = pkbf(b.z, b.w);
  return o;
}

// async global->LDS, 16B/lane; LDS dest must be wave-uniform base + lane*16.
static __device__ __forceinline__ void gll16(const void* g, void* l) {
  __builtin_amdgcn_global_load_lds(
      (const __attribute__((address_space(1))) void*)g,
      (__attribute__((address_space(3))) void*)l, 16, 0, 0);
}

// ---------------- CSR build ----------------
extern "C" __global__ void k_hist(const int* __restrict__ rows, int* __restrict__ counts, int n) {
  int i = blockIdx.x * 256 + threadIdx.x;
  if (i < n) atomicAdd(&counts[rows[i]], 1);
}

extern "C" __global__ __launch_bounds__(256) void k_blocksum(
    const int* __restrict__ counts, int* __restrict__ bsum, int n) {
  __shared__ int s[256];
  int t = threadIdx.x;
  int i = blockIdx.x * 256 + t;
  s[t] = (i < n) ? counts[i] : 0;
  __syncthreads();
  for (int off = 128; off > 0; off >>= 1) {
    if (t < off) s[t] += s[t + off];
    __syncthreads();
  }
  if (t == 0) bsum[blockIdx.x] = s[0];
}

extern "C" __global__ __launch_bounds__(256) void k_scansums(
    const int* __restrict__ bsum, int* __restrict__ bpre, int* __restrict__ rp, int nb, int n) {
  __shared__ int s[256];
  int t = threadIdx.x;
  int v = (t < nb) ? bsum[t] : 0;
  s[t] = v;
  __syncthreads();
  for (int off = 1; off < 256; off <<= 1) {
    int u = (t >= off) ? s[t - off] : 0;
    __syncthreads();
    s[t] += u;
    __syncthreads();
  }
  if (t < nb) bpre[t] = s[t] - v;
  if (t == 255) rp[n] = s[255];
}

extern "C" __global__ __launch_bounds__(256) void k_scanfin(
    const int* __restrict__ counts, const int* __restrict__ bpre,
    int* __restrict__ rp, int* __restrict__ cur, int n) {
  __shared__ int s[256];
  int t = threadIdx.x;
  int i = blockIdx.x * 256 + t;
  int c = (i < n) ? counts[i] : 0;
  s[t] = c;
  __syncthreads();
  for (int off = 1; off < 256; off <<= 1) {
    int u = (t >= off) ? s[t - off] : 0;
    __syncthreads();
    s[t] += u;
    __syncthreads();
  }
  if (i < n) {
    int e = bpre[blockIdx.x] + s[t] - c;
    rp[i] = e;
    cur[i] = e;
  }
}

extern "C" __global__ void k_scatter(const int* __restrict__ rows, const int* __restrict__ cols,
    const float* __restrict__ vals, int* __restrict__ cur, int2* __restrict__ ep, int n) {
  int i = blockIdx.x * 256 + threadIdx.x;
  if (i < n) {
    int p = atomicAdd(&cur[rows[i]], 1);
    int2 e; e.x = cols[i]; e.y = __float_as_int(vals[i]);
    ep[p] = e;
  }
}

// ---------------- weight transpose-cast: W [K][N] fp32 -> WT [N][K] bf16 ----------------
extern "C" __global__ void k_transcast(const float* __restrict__ w, unsigned short* __restrict__ wt,
                                       int K, int N) {
  int k = blockIdx.x; int n = threadIdx.x;
  wt[(size_t)n * K + k] = f2bf(w[(size_t)k * N + n]);
}

// ---------------- GEMM1: C[NN][256] = x[NN][512](fp32) * W1T[256][512]^T, bf16 out ----------------
// BM=64 (4 waves x 16 rows), BN=128 (grid.y=2), full-K A-slab in LDS.
extern "C" __global__ __launch_bounds__(256, 2) void k_gemm1(
    const float* __restrict__ A, const unsigned short* __restrict__ BT,
    unsigned short* __restrict__ C) {
  __shared__ __align__(16) unsigned short sA[64 * 512];   // 64KB, wave-private quadrants
  int tid = threadIdx.x;
  int lane = tid & 63, wid = tid >> 6;
  int l15 = lane & 15, lq = lane >> 4;
  int bm = blockIdx.x * 64, bn = blockIdx.y * 128;

  // ---- A-phase: wave w streams rows [bm+w*16, +16) = 32KB contiguous.
  // Per row: lane covers elements lane*8..+7 (32B of the 2KB row), cvt_pk
  // -> 16B unit, swizzled ds_write at unit (lane ^ (row&7)). 4-deep rolling
  // reg pipeline; compiler inserts counted waits (reg-only pipeline).
  {
    float4 ra[4][2];
    auto issue = [&](int i) {
      int ga = bm + wid * 16 + i; if (ga >= NN) ga = NN - 1;
      const float* src = A + (size_t)ga * NF + lane * 8;
      ra[i & 3][0] = ((const float4*)src)[0];
      ra[i & 3][1] = ((const float4*)src)[1];
    };
    issue(0); issue(1); issue(2); issue(3);
#pragma unroll
    for (int i = 0; i < 16; ++i) {
      int row = wid * 16 + i;
      uint4 w = pk8(ra[i & 3][0], ra[i & 3][1]);
      *(uint4*)(&sA[row * 512 + (lane ^ (row & 7)) * 8]) = w;
      if (i < 12) issue(i + 4);
    }
  }
  // no barrier: each wave reads only the quadrant it wrote.

  const unsigned short* bp[8];
#pragma unroll
  for (int nt = 0; nt < 8; ++nt)
    bp[nt] = BT + (size_t)(bn + nt * 16 + l15) * NF + lq * 8;

  f32x4 acc[8];
#pragma unroll
  for (int i = 0; i < 8; ++i) acc[i] = (f32x4){0.f, 0.f, 0.f, 0.f};

  // B register double-buffer, 1 phase ahead (16 phases = 8 t-steps x 2 ks).
  bf16x8 bpf[2][8];
#pragma unroll
  for (int nt = 0; nt < 8; ++nt) bpf[0][nt] = *(const bf16x8*)(bp[nt]);

  int arow = wid * 16 + l15;
  int aswz = arow & 7;
#pragma unroll
  for (int p = 0; p < 16; ++p) {
    if (p < 15) {
      int koff = ((p + 1) >> 1) * 64 + ((p + 1) & 1) * 32;
#pragma unroll
      for (int nt = 0; nt < 8; ++nt)
        bpf[(p + 1) & 1][nt] = *(const bf16x8*)(bp[nt] + koff);
    }
    int u = (((p >> 1) * 8) + ((p & 1) * 4) + lq) ^ aswz;
    bf16x8 af = *(const bf16x8*)(&sA[arow * 512 + u * 8]);
#pragma unroll
    for (int nt = 0; nt < 8; ++nt)
      acc[nt] = __builtin_amdgcn_mfma_f32_16x16x32_bf16(af, bpf[p & 1][nt], acc[nt], 0, 0, 0);
  }

#pragma unroll
  for (int nt = 0; nt < 8; ++nt) {
#pragma unroll
    for (int r = 0; r < 4; ++r) {
      int gr = bm + wid * 16 + lq * 4 + r;
      if (gr < NN) {
        int gc = bn + nt * 16 + l15;
        C[(size_t)gr * NH + gc] = f2bf(acc[nt][r]);
      }
    }
  }
}

// ---------------- GEMM2: C[NN][128] = h[NN][256](bf16) * W2T[128][256]^T, bf16 out ----------------
// BM=64, BN=128 (full NL), full-K A-slab (32KB) via gll16 w/ swizzled global
// source; one __syncthreads (drains the gll16s); B reg-prefetch; 8 phases.
extern "C" __global__ __launch_bounds__(256, 2) void k_gemm2(
    const unsigned short* __restrict__ Ah, const unsigned short* __restrict__ BT,
    unsigned short* __restrict__ C) {
  __shared__ __align__(16) unsigned short sA[64 * 256];   // 32KB
  int tid = threadIdx.x;
  int lane = tid & 63, wid = tid >> 6;
  int l15 = lane & 15, lq = lane >> 4;
  int bm = blockIdx.x * 64;

  // A-slab: 64 rows x 32 units(16B), 2048 units, 8 gll16/thread.
  // LDS linear; global source unit pre-swizzled g = cu ^ (row&7).
#pragma unroll
  for (int j = 0; j < 8; ++j) {
    int u = tid + 256 * j;
    int row = u >> 5, cu = u & 31;
    int ga = bm + row; if (ga >= NN) ga = NN - 1;
    int g = cu ^ (row & 7);
    gll16(Ah + (size_t)ga * NH + g * 8, &sA[u * 8]);
  }
  __syncthreads();   // vmcnt(0) drain == gll16 completion, then all waves read

  const unsigned short* bp[8];
#pragma unroll
  for (int nt = 0; nt < 8; ++nt)
    bp[nt] = BT + (size_t)(nt * 16 + l15) * NH + lq * 8;

  f32x4 acc[8];
#pragma unroll
  for (int i = 0; i < 8; ++i) acc[i] = (f32x4){0.f, 0.f, 0.f, 0.f};

  bf16x8 bpf[2][8];
#pragma unroll
  for (int nt = 0; nt < 8; ++nt) bpf[0][nt] = *(const bf16x8*)(bp[nt]);

  int arow = wid * 16 + l15;
  int aswz = arow & 7;
#pragma unroll
  for (int p = 0; p < 8; ++p) {   // 4 t-steps x 2 ks
    if (p < 7) {
      int koff = ((p + 1) >> 1) * 64 + ((p + 1) & 1) * 32;
#pragma unroll
      for (int nt = 0; nt < 8; ++nt)
        bpf[(p + 1) & 1][nt] = *(const bf16x8*)(bp[nt] + koff);
    }
    int u = (((p >> 1) * 8) + ((p & 1) * 4) + lq) ^ aswz;
    bf16x8 af = *(const bf16x8*)(&sA[arow * 256 + u * 8]);
#pragma unroll
    for (int nt = 0; nt < 8; ++nt)
      acc[nt] = __builtin_amdgcn_mfma_f32_16x16x32_bf16(af, bpf[p & 1][nt], acc[nt], 0, 0, 0);
  }

#pragma unroll
  for (int nt = 0; nt < 8; ++nt) {
#pragma unroll
    for (int r = 0; r < 4; ++r) {
      int gr = bm + wid * 16 + lq * 4 + r;
      if (gr < NN) {
        int gc = nt * 16 + l15;
        C[(size_t)gr * NL + gc] = f2bf(acc[nt][r]);
      }
    }
  }
}

// ---------------- SpMM (CSR row-gather), bf16 src, unroll-8/4/1, fused bias+relu ----------------
extern "C" __global__ __launch_bounds__(256) void k_spmm256(
    const int* __restrict__ rp, const int2* __restrict__ ep,
    const unsigned short* __restrict__ src, const float* __restrict__ bias,
    ushort4* __restrict__ out) {
  int row = blockIdx.x * 4 + (threadIdx.x >> 6);
  int lane = threadIdx.x & 63;
  if (row >= NN) return;
  int e0 = __builtin_amdgcn_readfirstlane(rp[row]);
  int e1 = __builtin_amdgcn_readfirstlane(rp[row + 1]);
  const ushort4* srcv = (const ushort4*)src;
  float4 acc = {0.f, 0.f, 0.f, 0.f};
  int e = e0;
  for (; e + 8 <= e1; e += 8) {
    int2 p[8]; ushort4 g[8];
#pragma unroll
    for (int j = 0; j < 8; ++j) p[j] = ep[e + j];
#pragma unroll
    for (int j = 0; j < 8; ++j) g[j] = srcv[(size_t)p[j].x * (NH / 4) + lane];
#pragma unroll
    for (int j = 0; j < 8; ++j) {
      float v = __int_as_float(p[j].y);
      acc.x = fmaf(v, bf2f(g[j].x), acc.x); acc.y = fmaf(v, bf2f(g[j].y), acc.y);
      acc.z = fmaf(v, bf2f(g[j].z), acc.z); acc.w = fmaf(v, bf2f(g[j].w), acc.w);
    }
  }
  for (; e + 4 <= e1; e += 4) {
    int2 p[4]; ushort4 g[4];
#pragma unroll
    for (int j = 0; j < 4; ++j) p[j] = ep[e + j];
#pragma unroll
    for (int j = 0; j < 4; ++j) g[j] = srcv[(size_t)p[j].x * (NH / 4) + lane];
#pragma unroll
    for (int j = 0; j < 4; ++j) {
      float v = __int_as_float(p[j].y);
      acc.x = fmaf(v, bf2f(g[j].x), acc.x); acc.y = fmaf(v, bf2f(g[j].y), acc.y);
      acc.z = fmaf(v, bf2f(g[j].z), acc.z); acc.w = fmaf(v, bf2f(g[j].w), acc.w);
    }
  }
  for (; e < e1; ++e) {
    int2 p = ep[e];
    float v = __int_as_float(p.y);
    ushort4 g = srcv[(size_t)p.x * (NH / 4) + lane];
    acc.x = fmaf(v, bf2f(g.x), acc.x); acc.y = fmaf(v, bf2f(g.y), acc.y);
    acc.z = fmaf(v, bf2f(g.z), acc.z); acc.w = fmaf(v, bf2f(g.w), acc.w);
  }
  float4 b = ((const float4*)bias)[lane];
  ushort4 o;
  o.x = f2bf(fmaxf(acc.x + b.x, 0.f));
  o.y = f2bf(fmaxf(acc.y + b.y, 0.f));
  o.z = f2bf(fmaxf(acc.z + b.z, 0.f));
  o.w = f2bf(fmaxf(acc.w + b.w, 0.f));
  out[(size_t)row * (NH / 4) + lane] = o;
}

extern "C" __global__ __launch_bounds__(256) void k_spmm128(
    const int* __restrict__ rp, const int2* __restrict__ ep,
    const unsigned short* __restrict__ src, const float* __restrict__ bias,
    float2* __restrict__ out) {
  int row = blockIdx.x * 4 + (threadIdx.x >> 6);
  int lane = threadIdx.x & 63;
  if (row >= NN) return;
  int e0 = __builtin_amdgcn_readfirstlane(rp[row]);
  int e1 = __builtin_amdgcn_readfirstlane(rp[row + 1]);
  const ushort2* srcv = (const ushort2*)src;
  float2 acc = {0.f, 0.f};
  int e = e0;
  for (; e + 8 <= e1; e += 8) {
    int2 p[8]; ushort2 g[8];
#pragma unroll
    for (int j = 0; j < 8; ++j) p[j] = ep[e + j];
#pragma unroll
    for (int j = 0; j < 8; ++j) g[j] = srcv[(size_t)p[j].x * (NL / 2) + lane];
#pragma unroll
    for (int j = 0; j < 8; ++j) {
      float v = __int_as_float(p[j].y);
      acc.x = fmaf(v, bf2f(g[j].x), acc.x); acc.y = fmaf(v, bf2f(g[j].y), acc.y);
    }
  }
  for (; e + 4 <= e1; e += 4) {
    int2 p[4]; ushort2 g[4];
#pragma unroll
    for (int j = 0; j < 4; ++j) p[j] = ep[e + j];
#pragma unroll
    for (int j = 0; j < 4; ++j) g[j] = srcv[(size_t)p[j].x * (NL / 2) + lane];
#pragma unroll
    for (int j = 0; j < 4; ++j) {
      float v = __int_as_float(p[j].y);
      acc.x = fmaf(v, bf2f(g[j].x), acc.x); acc.y = fmaf(v, bf2f(g[j].y), acc.y);
    }
  }
  for (; e < e1; ++e) {
    int2 p = ep[e];
    float v = __int_as_float(p.y);
    ushort2 g = srcv[(size_t)p.x * (NL / 2) + lane];
    acc.x = fmaf(v, bf2f(g.x), acc.x); acc.y = fmaf(v, bf2f(g.y), acc.y);
  }
  float2 b = ((const float2*)bias)[lane];
  float2 o;
  o.x = fmaxf(acc.x + b.x, 0.f);
  o.y = fmaxf(acc.y + b.y, 0.f);
  out[(size_t)row * (NL / 2) + lane] = o;
}

// ---------------- launch ----------------
extern "C" void kernel_launch(void* const* d_in, const int* in_sizes, int n_in,
                              void* d_out, int out_size, void* d_ws, size_t ws_size,
                              hipStream_t stream) {
  const float* x   = (const float*)d_in[0];
  const int* erow  = (const int*)d_in[1];
  const int* ecol  = (const int*)d_in[2];
  const float* ev  = (const float*)d_in[3];
  const float* W1  = (const float*)d_in[4];
  const float* b1  = (const float*)d_in[5];
  const float* W2  = (const float*)d_in[6];
  const float* b2  = (const float*)d_in[7];

  char* ws = (char*)d_ws;
  unsigned short* xwb = (unsigned short*)(ws + 0);           // 25,600,000 (x@W1 bf16)
  unsigned short* hbf = (unsigned short*)(ws + 25600000);    // 25,600,000 (h bf16)
  unsigned short* hwb = (unsigned short*)(ws + 51200000);    // 12,800,000 (h@W2 bf16)
  unsigned short* w1t = (unsigned short*)(ws + 64000000);    // 262,144
  unsigned short* w2t = (unsigned short*)(ws + 64262144);    // 65,536
  int* rp    = (int*)(ws + 64327680);                        // 200,704
  int* cur   = (int*)(ws + 64528384);                        // 200,704
  int* cnt   = (int*)(ws + 64729088);                        // 200,704
  int* bsum  = (int*)(ws + 64929792);                        // 1,024
  int* bpre  = (int*)(ws + 64930816);                        // 1,024
  int2* ep   = (int2*)(ws + 64931840);                       // 6,400,000

  // CSR build
  hipMemsetAsync(cnt, 0, NN * sizeof(int), stream);
  k_hist<<<NE / 256, 256, 0, stream>>>(erow, cnt, NE);
  k_blocksum<<<NB, 256, 0, stream>>>(cnt, bsum, NN);
  k_scansums<<<1, 256, 0, stream>>>(bsum, bpre, rp, NB, NN);
  k_scanfin<<<NB, 256, 0, stream>>>(cnt, bpre, rp, cur, NN);
  k_scatter<<<NE / 256, 256, 0, stream>>>(erow, ecol, ev, cur, ep, NE);

  // layer 1
  k_transcast<<<NF, NH, 0, stream>>>(W1, w1t, NF, NH);
  k_gemm1<<<dim3((NN + 63) / 64, NH / 128), 256, 0, stream>>>(x, w1t, xwb);
  k_spmm256<<<NN / 4, 256, 0, stream>>>(rp, ep, xwb, b1, (ushort4*)hbf);

  // layer 2
  k_transcast<<<NH, NL, 0, stream>>>(W2, w2t, NH, NL);
  k_gemm2<<<(NN + 63) / 64, 256, 0, stream>>>(hbf, w2t, hwb);
  k_spmm128<<<NN / 4, 256, 0, stream>>>(rp, ep, hwb, b2, (float2*)d_out);
}

// Round 9
// 415.479 us; speedup vs baseline: 1.1653x; 1.1653x over previous
//
#include <hip/hip_runtime.h>
#include <hip/hip_bf16.h>

// GCN encoder: z = relu(A @ relu(A @ (x@W1) + b1) @ W2 + b2)
// R14: load-B-once + barrier-free K-loop. Matrix of R6-R13 results:
//   B LDS-amortized + per-step barriers  -> 60-70us @ 2TB/s (5 schedules)
//   B not amortized                      -> 140-150us (R10, R13)
// Untested cell: B amortized with ZERO K-loop barriers. Hypothesis: the
// limiter is barrier-coupling of heterogeneous-latency loads (4 waves
// rendezvous every step at the slowest wave's A latency). Structure:
//   BN=64 -> full B panel (64x512 bf16 = 64KB) in LDS, loaded ONCE via
//   swizzled-source gll16; ONE __syncthreads (vmcnt0 drain = panel ready);
//   then 16 barrier-free phases: B from LDS (conflict-free swizzle),
//   A per-lane direct-global rolling 4-deep static-slot prefetch + cvt_pk.
//   Reg-only pipeline -> compiler counted waits; waves self-pace.
// gemm2: same (full 128x256 B = 64KB, 8 phases).

typedef __attribute__((ext_vector_type(8))) short bf16x8;
typedef __attribute__((ext_vector_type(4))) float f32x4;

#define NN 50000
#define NE 800000
#define NF 512
#define NH 256
#define NL 128
#define NB ((NN + 255) / 256)

static __device__ __forceinline__ unsigned short f2bf(float f) {
  union { float f; unsigned int u; } v; v.f = f;
  unsigned int r = v.u + 0x7fffu + ((v.u >> 16) & 1u);   // RNE
  return (unsigned short)(r >> 16);
}
static __device__ __forceinline__ float bf2f(unsigned short u) {
  union { unsigned int u; float f; } v; v.u = (unsigned int)u << 16;
  return v.f;
}

// HW packed f32->bf16 (RNE), 2 elems / instruction (no builtin on gfx950).
static __device__ __forceinline__ unsigned int pkbf(float lo, float hi) {
  unsigned int r;
  asm("v_cvt_pk_bf16_f32 %0, %1, %2" : "=v"(r) : "v"(lo), "v"(hi));
  return r;
}
static __device__ __forceinline__ uint4 pk8(float4 a, float4 b) {
  uint4 o;
  o.x = pkbf(a.x, a.y); o.y = pkbf(a.z, a.w);
  o.z = pkbf(b.x, b.y); o.w = pkbf(b.z, b.w);
  return o;
}

// async global->LDS, 16B/lane; LDS dest must be wave-uniform base + lane*16.
static __device__ __forceinline__ void gll16(const void* g, void* l) {
  __builtin_amdgcn_global_load_lds(
      (const __attribute__((address_space(1))) void*)g,
      (__attribute__((address_space(3))) void*)l, 16, 0, 0);
}

// ---------------- CSR build ----------------
extern "C" __global__ void k_hist(const int* __restrict__ rows, int* __restrict__ counts, int n) {
  int i = blockIdx.x * 256 + threadIdx.x;
  if (i < n) atomicAdd(&counts[rows[i]], 1);
}

extern "C" __global__ __launch_bounds__(256) void k_blocksum(
    const int* __restrict__ counts, int* __restrict__ bsum, int n) {
  __shared__ int s[256];
  int t = threadIdx.x;
  int i = blockIdx.x * 256 + t;
  s[t] = (i < n) ? counts[i] : 0;
  __syncthreads();
  for (int off = 128; off > 0; off >>= 1) {
    if (t < off) s[t] += s[t + off];
    __syncthreads();
  }
  if (t == 0) bsum[blockIdx.x] = s[0];
}

extern "C" __global__ __launch_bounds__(256) void k_scansums(
    const int* __restrict__ bsum, int* __restrict__ bpre, int* __restrict__ rp, int nb, int n) {
  __shared__ int s[256];
  int t = threadIdx.x;
  int v = (t < nb) ? bsum[t] : 0;
  s[t] = v;
  __syncthreads();
  for (int off = 1; off < 256; off <<= 1) {
    int u = (t >= off) ? s[t - off] : 0;
    __syncthreads();
    s[t] += u;
    __syncthreads();
  }
  if (t < nb) bpre[t] = s[t] - v;
  if (t == 255) rp[n] = s[255];
}

extern "C" __global__ __launch_bounds__(256) void k_scanfin(
    const int* __restrict__ counts, const int* __restrict__ bpre,
    int* __restrict__ rp, int* __restrict__ cur, int n) {
  __shared__ int s[256];
  int t = threadIdx.x;
  int i = blockIdx.x * 256 + t;
  int c = (i < n) ? counts[i] : 0;
  s[t] = c;
  __syncthreads();
  for (int off = 1; off < 256; off <<= 1) {
    int u = (t >= off) ? s[t - off] : 0;
    __syncthreads();
    s[t] += u;
    __syncthreads();
  }
  if (i < n) {
    int e = bpre[blockIdx.x] + s[t] - c;
    rp[i] = e;
    cur[i] = e;
  }
}

extern "C" __global__ void k_scatter(const int* __restrict__ rows, const int* __restrict__ cols,
    const float* __restrict__ vals, int* __restrict__ cur, int2* __restrict__ ep, int n) {
  int i = blockIdx.x * 256 + threadIdx.x;
  if (i < n) {
    int p = atomicAdd(&cur[rows[i]], 1);
    int2 e; e.x = cols[i]; e.y = __float_as_int(vals[i]);
    ep[p] = e;
  }
}

// ---------------- weight transpose-cast: W [K][N] fp32 -> WT [N][K] bf16 ----------------
extern "C" __global__ void k_transcast(const float* __restrict__ w, unsigned short* __restrict__ wt,
                                       int K, int N) {
  int k = blockIdx.x; int n = threadIdx.x;
  wt[(size_t)n * K + k] = f2bf(w[(size_t)k * N + n]);
}

// ---------------- GEMM1: C[NN][256] = x[NN][512](fp32) * W1T[256][512]^T, bf16 out ----------------
// BM=64 (4 waves x 16 rows), BN=64, grid (782,4). Full B panel in LDS once;
// one barrier total; 16 barrier-free phases.
extern "C" __global__ __launch_bounds__(256, 2) void k_gemm1(
    const float* __restrict__ A, const unsigned short* __restrict__ BT,
    unsigned short* __restrict__ C) {
  __shared__ __align__(16) unsigned short sB[64 * 512];   // 64KB: [col][K]
  int tid = threadIdx.x;
  int lane = tid & 63, wid = tid >> 6;
  int l15 = lane & 15, lq = lane >> 4;
  int bm = blockIdx.x * 64, bn = blockIdx.y * 64;

  // ---- one-time B panel load: 64 cols x 512 K = 4096 16B-units, 16/thread.
  // LDS linear (unit u -> u*16B); global source unit swizzled g = cu^(row&7)
  // so LDS[row][cu] holds global unit cu^(row&7) (involution with the read).
#pragma unroll
  for (int j = 0; j < 16; ++j) {
    int u = tid + 256 * j;
    int row = u >> 6, cu = u & 63;
    int g = cu ^ (row & 7);
    gll16(BT + (size_t)(bn + row) * NF + g * 8, &sB[u * 8]);
  }

  int arow = bm + wid * 16 + l15; if (arow >= NN) arow = NN - 1;
  const float* ap = A + (size_t)arow * NF + lq * 8;

  // prologue A prefetch: phases 0..3 (4-deep static slots)
  float4 apf[4][2];
#pragma unroll
  for (int p = 0; p < 4; ++p) {
    apf[p][0] = *(const float4*)(ap + p * 32);
    apf[p][1] = *(const float4*)(ap + p * 32 + 4);
  }

  __syncthreads();   // vmcnt(0) drain: B panel resident. LAST barrier.

  f32x4 acc[4];
#pragma unroll
  for (int i = 0; i < 4; ++i) acc[i] = (f32x4){0.f, 0.f, 0.f, 0.f};

  // ---- 16 phases of K=32, no barriers: B read-only LDS, A reg pipeline.
#pragma unroll
  for (int p = 0; p < 16; ++p) {
    bf16x8 bfr[4];
#pragma unroll
    for (int nt = 0; nt < 4; ++nt) {
      int c = nt * 16 + l15;
      int u = (p * 4 + lq) ^ (c & 7);
      bfr[nt] = *(const bf16x8*)(&sB[c * 512 + u * 8]);
    }
    union { uint4 u; bf16x8 v; } cv;
    cv.u = pk8(apf[p & 3][0], apf[p & 3][1]);
    bf16x8 af = cv.v;
    if (p < 12) {   // refill the just-freed slot, 4 phases ahead
      apf[p & 3][0] = *(const float4*)(ap + (p + 4) * 32);
      apf[p & 3][1] = *(const float4*)(ap + (p + 4) * 32 + 4);
    }
#pragma unroll
    for (int nt = 0; nt < 4; ++nt)
      acc[nt] = __builtin_amdgcn_mfma_f32_16x16x32_bf16(af, bfr[nt], acc[nt], 0, 0, 0);
  }

#pragma unroll
  for (int nt = 0; nt < 4; ++nt) {
#pragma unroll
    for (int r = 0; r < 4; ++r) {
      int gr = bm + wid * 16 + lq * 4 + r;
      if (gr < NN) {
        int gc = bn + nt * 16 + l15;
        C[(size_t)gr * NH + gc] = f2bf(acc[nt][r]);
      }
    }
  }
}

// ---------------- GEMM2: C[NN][128] = h[NN][256](bf16) * W2T[128][256]^T, bf16 out ----------------
// Full B (128x256 = 64KB) in LDS once; 8 barrier-free phases; A bf16 4-deep.
extern "C" __global__ __launch_bounds__(256, 2) void k_gemm2(
    const unsigned short* __restrict__ Ah, const unsigned short* __restrict__ BT,
    unsigned short* __restrict__ C) {
  __shared__ __align__(16) unsigned short sB[128 * 256];   // 64KB: [col][K]
  int tid = threadIdx.x;
  int lane = tid & 63, wid = tid >> 6;
  int l15 = lane & 15, lq = lane >> 4;
  int bm = blockIdx.x * 64;

  // B: 128 cols x 32 units(16B) = 4096 units, 16/thread, swizzled source.
#pragma unroll
  for (int j = 0; j < 16; ++j) {
    int u = tid + 256 * j;
    int row = u >> 5, cu = u & 31;
    int g = cu ^ (row & 7);
    gll16(BT + (size_t)row * NH + g * 8, &sB[u * 8]);
  }

  int arow = bm + wid * 16 + l15; if (arow >= NN) arow = NN - 1;
  const unsigned short* ap = Ah + (size_t)arow * NH + lq * 8;

  bf16x8 apf[4];
#pragma unroll
  for (int p = 0; p < 4; ++p) apf[p] = *(const bf16x8*)(ap + p * 32);

  __syncthreads();   // B resident. LAST barrier.

  f32x4 acc[8];
#pragma unroll
  for (int i = 0; i < 8; ++i) acc[i] = (f32x4){0.f, 0.f, 0.f, 0.f};

#pragma unroll
  for (int p = 0; p < 8; ++p) {
    bf16x8 bfr[8];
#pragma unroll
    for (int nt = 0; nt < 8; ++nt) {
      int c = nt * 16 + l15;
      int u = (p * 4 + lq) ^ (c & 7);
      bfr[nt] = *(const bf16x8*)(&sB[c * 256 + u * 8]);
    }
    bf16x8 af = apf[p & 3];
    if (p < 4) apf[p & 3] = *(const bf16x8*)(ap + (p + 4) * 32);
#pragma unroll
    for (int nt = 0; nt < 8; ++nt)
      acc[nt] = __builtin_amdgcn_mfma_f32_16x16x32_bf16(af, bfr[nt], acc[nt], 0, 0, 0);
  }

#pragma unroll
  for (int nt = 0; nt < 8; ++nt) {
#pragma unroll
    for (int r = 0; r < 4; ++r) {
      int gr = bm + wid * 16 + lq * 4 + r;
      if (gr < NN) {
        int gc = nt * 16 + l15;
        C[(size_t)gr * NL + gc] = f2bf(acc[nt][r]);
      }
    }
  }
}

// ---------------- SpMM (CSR row-gather), bf16 src, unroll-8/4/1, fused bias+relu ----------------
extern "C" __global__ __launch_bounds__(256) void k_spmm256(
    const int* __restrict__ rp, const int2* __restrict__ ep,
    const unsigned short* __restrict__ src, const float* __restrict__ bias,
    ushort4* __restrict__ out) {
  int row = blockIdx.x * 4 + (threadIdx.x >> 6);
  int lane = threadIdx.x & 63;
  if (row >= NN) return;
  int e0 = __builtin_amdgcn_readfirstlane(rp[row]);
  int e1 = __builtin_amdgcn_readfirstlane(rp[row + 1]);
  const ushort4* srcv = (const ushort4*)src;
  float4 acc = {0.f, 0.f, 0.f, 0.f};
  int e = e0;
  for (; e + 8 <= e1; e += 8) {
    int2 p[8]; ushort4 g[8];
#pragma unroll
    for (int j = 0; j < 8; ++j) p[j] = ep[e + j];
#pragma unroll
    for (int j = 0; j < 8; ++j) g[j] = srcv[(size_t)p[j].x * (NH / 4) + lane];
#pragma unroll
    for (int j = 0; j < 8; ++j) {
      float v = __int_as_float(p[j].y);
      acc.x = fmaf(v, bf2f(g[j].x), acc.x); acc.y = fmaf(v, bf2f(g[j].y), acc.y);
      acc.z = fmaf(v, bf2f(g[j].z), acc.z); acc.w = fmaf(v, bf2f(g[j].w), acc.w);
    }
  }
  for (; e + 4 <= e1; e += 4) {
    int2 p[4]; ushort4 g[4];
#pragma unroll
    for (int j = 0; j < 4; ++j) p[j] = ep[e + j];
#pragma unroll
    for (int j = 0; j < 4; ++j) g[j] = srcv[(size_t)p[j].x * (NH / 4) + lane];
#pragma unroll
    for (int j = 0; j < 4; ++j) {
      float v = __int_as_float(p[j].y);
      acc.x = fmaf(v, bf2f(g[j].x), acc.x); acc.y = fmaf(v, bf2f(g[j].y), acc.y);
      acc.z = fmaf(v, bf2f(g[j].z), acc.z); acc.w = fmaf(v, bf2f(g[j].w), acc.w);
    }
  }
  for (; e < e1; ++e) {
    int2 p = ep[e];
    float v = __int_as_float(p.y);
    ushort4 g = srcv[(size_t)p.x * (NH / 4) + lane];
    acc.x = fmaf(v, bf2f(g.x), acc.x); acc.y = fmaf(v, bf2f(g.y), acc.y);
    acc.z = fmaf(v, bf2f(g.z), acc.z); acc.w = fmaf(v, bf2f(g.w), acc.w);
  }
  float4 b = ((const float4*)bias)[lane];
  ushort4 o;
  o.x = f2bf(fmaxf(acc.x + b.x, 0.f));
  o.y = f2bf(fmaxf(acc.y + b.y, 0.f));
  o.z = f2bf(fmaxf(acc.z + b.z, 0.f));
  o.w = f2bf(fmaxf(acc.w + b.w, 0.f));
  out[(size_t)row * (NH / 4) + lane] = o;
}

extern "C" __global__ __launch_bounds__(256) void k_spmm128(
    const int* __restrict__ rp, const int2* __restrict__ ep,
    const unsigned short* __restrict__ src, const float* __restrict__ bias,
    float2* __restrict__ out) {
  int row = blockIdx.x * 4 + (threadIdx.x >> 6);
  int lane = threadIdx.x & 63;
  if (row >= NN) return;
  int e0 = __builtin_amdgcn_readfirstlane(rp[row]);
  int e1 = __builtin_amdgcn_readfirstlane(rp[row + 1]);
  const ushort2* srcv = (const ushort2*)src;
  float2 acc = {0.f, 0.f};
  int e = e0;
  for (; e + 8 <= e1; e += 8) {
    int2 p[8]; ushort2 g[8];
#pragma unroll
    for (int j = 0; j < 8; ++j) p[j] = ep[e + j];
#pragma unroll
    for (int j = 0; j < 8; ++j) g[j] = srcv[(size_t)p[j].x * (NL / 2) + lane];
#pragma unroll
    for (int j = 0; j < 8; ++j) {
      float v = __int_as_float(p[j].y);
      acc.x = fmaf(v, bf2f(g[j].x), acc.x); acc.y = fmaf(v, bf2f(g[j].y), acc.y);
    }
  }
  for (; e + 4 <= e1; e += 4) {
    int2 p[4]; ushort2 g[4];
#pragma unroll
    for (int j = 0; j < 4; ++j) p[j] = ep[e + j];
#pragma unroll
    for (int j = 0; j < 4; ++j) g[j] = srcv[(size_t)p[j].x * (NL / 2) + lane];
#pragma unroll
    for (int j = 0; j < 4; ++j) {
      float v = __int_as_float(p[j].y);
      acc.x = fmaf(v, bf2f(g[j].x), acc.x); acc.y = fmaf(v, bf2f(g[j].y), acc.y);
    }
  }
  for (; e < e1; ++e) {
    int2 p = ep[e];
    float v = __int_as_float(p.y);
    ushort2 g = srcv[(size_t)p.x * (NL / 2) + lane];
    acc.x = fmaf(v, bf2f(g.x), acc.x); acc.y = fmaf(v, bf2f(g.y), acc.y);
  }
  float2 b = ((const float2*)bias)[lane];
  float2 o;
  o.x = fmaxf(acc.x + b.x, 0.f);
  o.y = fmaxf(acc.y + b.y, 0.f);
  out[(size_t)row * (NL / 2) + lane] = o;
}

// ---------------- launch ----------------
extern "C" void kernel_launch(void* const* d_in, const int* in_sizes, int n_in,
                              void* d_out, int out_size, void* d_ws, size_t ws_size,
                              hipStream_t stream) {
  const float* x   = (const float*)d_in[0];
  const int* erow  = (const int*)d_in[1];
  const int* ecol  = (const int*)d_in[2];
  const float* ev  = (const float*)d_in[3];
  const float* W1  = (const float*)d_in[4];
  const float* b1  = (const float*)d_in[5];
  const float* W2  = (const float*)d_in[6];
  const float* b2  = (const float*)d_in[7];

  char* ws = (char*)d_ws;
  unsigned short* xwb = (unsigned short*)(ws + 0);           // 25,600,000 (x@W1 bf16)
  unsigned short* hbf = (unsigned short*)(ws + 25600000);    // 25,600,000 (h bf16)
  unsigned short* hwb = (unsigned short*)(ws + 51200000);    // 12,800,000 (h@W2 bf16)
  unsigned short* w1t = (unsigned short*)(ws + 64000000);    // 262,144
  unsigned short* w2t = (unsigned short*)(ws + 64262144);    // 65,536
  int* rp    = (int*)(ws + 64327680);                        // 200,704
  int* cur   = (int*)(ws + 64528384);                        // 200,704
  int* cnt   = (int*)(ws + 64729088);                        // 200,704
  int* bsum  = (int*)(ws + 64929792);                        // 1,024
  int* bpre  = (int*)(ws + 64930816);                        // 1,024
  int2* ep   = (int2*)(ws + 64931840);                       // 6,400,000

  // CSR build
  hipMemsetAsync(cnt, 0, NN * sizeof(int), stream);
  k_hist<<<NE / 256, 256, 0, stream>>>(erow, cnt, NE);
  k_blocksum<<<NB, 256, 0, stream>>>(cnt, bsum, NN);
  k_scansums<<<1, 256, 0, stream>>>(bsum, bpre, rp, NB, NN);
  k_scanfin<<<NB, 256, 0, stream>>>(cnt, bpre, rp, cur, NN);
  k_scatter<<<NE / 256, 256, 0, stream>>>(erow, ecol, ev, cur, ep, NE);

  // layer 1
  k_transcast<<<NF, NH, 0, stream>>>(W1, w1t, NF, NH);
  k_gemm1<<<dim3((NN + 63) / 64, 4), 256, 0, stream>>>(x, w1t, xwb);
  k_spmm256<<<NN / 4, 256, 0, stream>>>(rp, ep, xwb, b1, (ushort4*)hbf);

  // layer 2
  k_transcast<<<NH, NL, 0, stream>>>(W2, w2t, NH, NL);
  k_gemm2<<<(NN + 63) / 64, 256, 0, stream>>>(hbf, w2t, hwb);
  k_spmm128<<<NN / 4, 256, 0, stream>>>(rp, ep, hwb, b2, (float2*)d_out);
}

// Round 10
// 382.220 us; speedup vs baseline: 1.2667x; 1.0870x over previous
//
#include <hip/hip_runtime.h>
#include <hip/hip_bf16.h>

// GCN encoder: z = relu(A @ relu(A @ (x@W1) + b1) @ W2 + b2)
// R15: A-in-registers + rotating B panels, barrier-free K-loop. R14 proved the
// barrier-free structure lifts HBM service 2.0->2.5 TB/s, but BN=64 doubled
// FETCH (202MB: 4 panels x full A, L3 absorbed half) -> 93us = 232MB/2.5TB/s
// exactly. Now: BM=64, block computes ALL 256 out-cols. Each wave cvt_pk's its
// 16 A-rows into VGPR fragments (abf[16], 64 VGPR) during panel 0; loops 8
// B-panels of 32 cols (32KB LDS each, double-buffered = 64KB -> 2 blocks/CU).
// Panel q+1's gll16s issued before panel q's compute, drained at the single
// per-panel __syncthreads (8 barriers total, none inside the K-phases).
// A read ONCE (101MB), B L2-resident (256KB), C 25MB -> ~130MB @ >=2.5TB/s.

typedef __attribute__((ext_vector_type(8))) short bf16x8;
typedef __attribute__((ext_vector_type(4))) float f32x4;

#define NN 50000
#define NE 800000
#define NF 512
#define NH 256
#define NL 128
#define NB ((NN + 255) / 256)

static __device__ __forceinline__ unsigned short f2bf(float f) {
  union { float f; unsigned int u; } v; v.f = f;
  unsigned int r = v.u + 0x7fffu + ((v.u >> 16) & 1u);   // RNE
  return (unsigned short)(r >> 16);
}
static __device__ __forceinline__ float bf2f(unsigned short u) {
  union { unsigned int u; float f; } v; v.u = (unsigned int)u << 16;
  return v.f;
}

// HW packed f32->bf16 (RNE), 2 elems / instruction (no builtin on gfx950).
static __device__ __forceinline__ unsigned int pkbf(float lo, float hi) {
  unsigned int r;
  asm("v_cvt_pk_bf16_f32 %0, %1, %2" : "=v"(r) : "v"(lo), "v"(hi));
  return r;
}
static __device__ __forceinline__ uint4 pk8(float4 a, float4 b) {
  uint4 o;
  o.x = pkbf(a.x, a.y); o.y = pkbf(a.z, a.w);
  o.z = pkbf(b.x, b.y); o.w = pkbf(b.z, b.w);
  return o;
}

// async global->LDS, 16B/lane; LDS dest must be wave-uniform base + lane*16.
static __device__ __forceinline__ void gll16(const void* g, void* l) {
  __builtin_amdgcn_global_load_lds(
      (const __attribute__((address_space(1))) void*)g,
      (__attribute__((address_space(3))) void*)l, 16, 0, 0);
}

// ---------------- CSR build ----------------
extern "C" __global__ void k_hist(const int* __restrict__ rows, int* __restrict__ counts, int n) {
  int i = blockIdx.x * 256 + threadIdx.x;
  if (i < n) atomicAdd(&counts[rows[i]], 1);
}

extern "C" __global__ __launch_bounds__(256) void k_blocksum(
    const int* __restrict__ counts, int* __restrict__ bsum, int n) {
  __shared__ int s[256];
  int t = threadIdx.x;
  int i = blockIdx.x * 256 + t;
  s[t] = (i < n) ? counts[i] : 0;
  __syncthreads();
  for (int off = 128; off > 0; off >>= 1) {
    if (t < off) s[t] += s[t + off];
    __syncthreads();
  }
  if (t == 0) bsum[blockIdx.x] = s[0];
}

extern "C" __global__ __launch_bounds__(256) void k_scansums(
    const int* __restrict__ bsum, int* __restrict__ bpre, int* __restrict__ rp, int nb, int n) {
  __shared__ int s[256];
  int t = threadIdx.x;
  int v = (t < nb) ? bsum[t] : 0;
  s[t] = v;
  __syncthreads();
  for (int off = 1; off < 256; off <<= 1) {
    int u = (t >= off) ? s[t - off] : 0;
    __syncthreads();
    s[t] += u;
    __syncthreads();
  }
  if (t < nb) bpre[t] = s[t] - v;
  if (t == 255) rp[n] = s[255];
}

extern "C" __global__ __launch_bounds__(256) void k_scanfin(
    const int* __restrict__ counts, const int* __restrict__ bpre,
    int* __restrict__ rp, int* __restrict__ cur, int n) {
  __shared__ int s[256];
  int t = threadIdx.x;
  int i = blockIdx.x * 256 + t;
  int c = (i < n) ? counts[i] : 0;
  s[t] = c;
  __syncthreads();
  for (int off = 1; off < 256; off <<= 1) {
    int u = (t >= off) ? s[t - off] : 0;
    __syncthreads();
    s[t] += u;
    __syncthreads();
  }
  if (i < n) {
    int e = bpre[blockIdx.x] + s[t] - c;
    rp[i] = e;
    cur[i] = e;
  }
}

extern "C" __global__ void k_scatter(const int* __restrict__ rows, const int* __restrict__ cols,
    const float* __restrict__ vals, int* __restrict__ cur, int2* __restrict__ ep, int n) {
  int i = blockIdx.x * 256 + threadIdx.x;
  if (i < n) {
    int p = atomicAdd(&cur[rows[i]], 1);
    int2 e; e.x = cols[i]; e.y = __float_as_int(vals[i]);
    ep[p] = e;
  }
}

// ---------------- weight transpose-cast: W [K][N] fp32 -> WT [N][K] bf16 ----------------
extern "C" __global__ void k_transcast(const float* __restrict__ w, unsigned short* __restrict__ wt,
                                       int K, int N) {
  int k = blockIdx.x; int n = threadIdx.x;
  wt[(size_t)n * K + k] = f2bf(w[(size_t)k * N + n]);
}

// ---------------- GEMM1: C[NN][256] = x[NN][512](fp32) * W1T[256][512]^T, bf16 out ----------------
// BM=64 (4 waves x 16 rows), all 256 cols per block via 8 B-panels of 32.
extern "C" __global__ __launch_bounds__(256, 2) void k_gemm1(
    const float* __restrict__ A, const unsigned short* __restrict__ BT,
    unsigned short* __restrict__ C) {
  __shared__ __align__(16) unsigned short sB[2][32 * 512];   // 2 x 32KB: [col][K]
  int tid = threadIdx.x;
  int lane = tid & 63, wid = tid >> 6;
  int l15 = lane & 15, lq = lane >> 4;
  int bm = blockIdx.x * 64;

  // B panel q (cols q*32..+31): 32 cols x 64 units(16B), 2048 units, 8/thread.
  // LDS linear; global source unit pre-swizzled g = cu^(c&7) (involution with read).
  auto issueB = [&](int q, int b) {
#pragma unroll
    for (int j = 0; j < 8; ++j) {
      int u = tid + 256 * j;
      int c = u >> 6, cu = u & 63;
      int g = cu ^ (c & 7);
      gll16(BT + (size_t)(q * 32 + c) * NF + g * 8, &sB[b][u * 8]);
    }
  };

  int arow = bm + wid * 16 + l15; if (arow >= NN) arow = NN - 1;
  const float* ap = A + (size_t)arow * NF + lq * 8;

  issueB(0, 0);
  float4 apf[4][2];   // 4-deep A prefetch (panel 0 only)
#pragma unroll
  for (int p = 0; p < 4; ++p) {
    apf[p][0] = *(const float4*)(ap + p * 32);
    apf[p][1] = *(const float4*)(ap + p * 32 + 4);
  }
  __syncthreads();          // B0 resident
  issueB(1, 1);             // flies under panel-0 compute

  bf16x8 abf[16];           // this wave's full A fragment set (64 VGPR)
  f32x4 acc[16];
#pragma unroll
  for (int i = 0; i < 16; ++i) acc[i] = (f32x4){0.f, 0.f, 0.f, 0.f};

  // ---- panel 0 (cols 0..31): A global loads + cvt + MFMA, barrier-free phases
#pragma unroll
  for (int p = 0; p < 16; ++p) {
    bf16x8 bfr[2];
#pragma unroll
    for (int nt = 0; nt < 2; ++nt) {
      int c = nt * 16 + l15;
      int u = (p * 4 + lq) ^ (c & 7);
      bfr[nt] = *(const bf16x8*)(&sB[0][c * 512 + u * 8]);
    }
    union { uint4 u; bf16x8 v; } cv;
    cv.u = pk8(apf[p & 3][0], apf[p & 3][1]);
    abf[p] = cv.v;
    if (p < 12) {   // refill freed slot 4 phases ahead
      apf[p & 3][0] = *(const float4*)(ap + (p + 4) * 32);
      apf[p & 3][1] = *(const float4*)(ap + (p + 4) * 32 + 4);
    }
#pragma unroll
    for (int nt = 0; nt < 2; ++nt)
      acc[nt] = __builtin_amdgcn_mfma_f32_16x16x32_bf16(abf[p], bfr[nt], acc[nt], 0, 0, 0);
  }
  __syncthreads();          // B1 resident; all waves done reading buf0

  // ---- panels 1..7: pure LDS+MFMA phases; issue next panel's B first
#pragma unroll
  for (int q = 1; q < 8; ++q) {
    if (q < 7) issueB(q + 1, (q + 1) & 1);
#pragma unroll
    for (int p = 0; p < 16; ++p) {
      bf16x8 bfr[2];
#pragma unroll
      for (int nt = 0; nt < 2; ++nt) {
        int c = nt * 16 + l15;
        int u = (p * 4 + lq) ^ (c & 7);
        bfr[nt] = *(const bf16x8*)(&sB[q & 1][c * 512 + u * 8]);
      }
#pragma unroll
      for (int nt = 0; nt < 2; ++nt)
        acc[q * 2 + nt] = __builtin_amdgcn_mfma_f32_16x16x32_bf16(abf[p], bfr[nt], acc[q * 2 + nt], 0, 0, 0);
    }
    if (q < 7) __syncthreads();   // drains B(q+1); waves done with buf[q&1]
  }

  // ---- epilogue: tile t covers cols t*16..+15
#pragma unroll
  for (int t = 0; t < 16; ++t) {
#pragma unroll
    for (int r = 0; r < 4; ++r) {
      int gr = bm + wid * 16 + lq * 4 + r;
      if (gr < NN) {
        int gc = t * 16 + l15;
        C[(size_t)gr * NH + gc] = f2bf(acc[t][r]);
      }
    }
  }
}

// ---------------- GEMM2: C[NN][128] = h[NN][256](bf16) * W2T[128][256]^T, bf16 out ----------------
// R14-verified: full B (128x256 = 64KB) in LDS once; 8 barrier-free phases.
extern "C" __global__ __launch_bounds__(256, 2) void k_gemm2(
    const unsigned short* __restrict__ Ah, const unsigned short* __restrict__ BT,
    unsigned short* __restrict__ C) {
  __shared__ __align__(16) unsigned short sB[128 * 256];   // 64KB: [col][K]
  int tid = threadIdx.x;
  int lane = tid & 63, wid = tid >> 6;
  int l15 = lane & 15, lq = lane >> 4;
  int bm = blockIdx.x * 64;

  // B: 128 cols x 32 units(16B) = 4096 units, 16/thread, swizzled source.
#pragma unroll
  for (int j = 0; j < 16; ++j) {
    int u = tid + 256 * j;
    int row = u >> 5, cu = u & 31;
    int g = cu ^ (row & 7);
    gll16(BT + (size_t)row * NH + g * 8, &sB[u * 8]);
  }

  int arow = bm + wid * 16 + l15; if (arow >= NN) arow = NN - 1;
  const unsigned short* ap = Ah + (size_t)arow * NH + lq * 8;

  bf16x8 apf[4];
#pragma unroll
  for (int p = 0; p < 4; ++p) apf[p] = *(const bf16x8*)(ap + p * 32);

  __syncthreads();   // B resident. LAST barrier.

  f32x4 acc[8];
#pragma unroll
  for (int i = 0; i < 8; ++i) acc[i] = (f32x4){0.f, 0.f, 0.f, 0.f};

#pragma unroll
  for (int p = 0; p < 8; ++p) {
    bf16x8 bfr[8];
#pragma unroll
    for (int nt = 0; nt < 8; ++nt) {
      int c = nt * 16 + l15;
      int u = (p * 4 + lq) ^ (c & 7);
      bfr[nt] = *(const bf16x8*)(&sB[c * 256 + u * 8]);
    }
    bf16x8 af = apf[p & 3];
    if (p < 4) apf[p & 3] = *(const bf16x8*)(ap + (p + 4) * 32);
#pragma unroll
    for (int nt = 0; nt < 8; ++nt)
      acc[nt] = __builtin_amdgcn_mfma_f32_16x16x32_bf16(af, bfr[nt], acc[nt], 0, 0, 0);
  }

#pragma unroll
  for (int nt = 0; nt < 8; ++nt) {
#pragma unroll
    for (int r = 0; r < 4; ++r) {
      int gr = bm + wid * 16 + lq * 4 + r;
      if (gr < NN) {
        int gc = nt * 16 + l15;
        C[(size_t)gr * NL + gc] = f2bf(acc[nt][r]);
      }
    }
  }
}

// ---------------- SpMM (CSR row-gather), bf16 src, unroll-8/4/1, fused bias+relu ----------------
extern "C" __global__ __launch_bounds__(256) void k_spmm256(
    const int* __restrict__ rp, const int2* __restrict__ ep,
    const unsigned short* __restrict__ src, const float* __restrict__ bias,
    ushort4* __restrict__ out) {
  int row = blockIdx.x * 4 + (threadIdx.x >> 6);
  int lane = threadIdx.x & 63;
  if (row >= NN) return;
  int e0 = __builtin_amdgcn_readfirstlane(rp[row]);
  int e1 = __builtin_amdgcn_readfirstlane(rp[row + 1]);
  const ushort4* srcv = (const ushort4*)src;
  float4 acc = {0.f, 0.f, 0.f, 0.f};
  int e = e0;
  for (; e + 8 <= e1; e += 8) {
    int2 p[8]; ushort4 g[8];
#pragma unroll
    for (int j = 0; j < 8; ++j) p[j] = ep[e + j];
#pragma unroll
    for (int j = 0; j < 8; ++j) g[j] = srcv[(size_t)p[j].x * (NH / 4) + lane];
#pragma unroll
    for (int j = 0; j < 8; ++j) {
      float v = __int_as_float(p[j].y);
      acc.x = fmaf(v, bf2f(g[j].x), acc.x); acc.y = fmaf(v, bf2f(g[j].y), acc.y);
      acc.z = fmaf(v, bf2f(g[j].z), acc.z); acc.w = fmaf(v, bf2f(g[j].w), acc.w);
    }
  }
  for (; e + 4 <= e1; e += 4) {
    int2 p[4]; ushort4 g[4];
#pragma unroll
    for (int j = 0; j < 4; ++j) p[j] = ep[e + j];
#pragma unroll
    for (int j = 0; j < 4; ++j) g[j] = srcv[(size_t)p[j].x * (NH / 4) + lane];
#pragma unroll
    for (int j = 0; j < 4; ++j) {
      float v = __int_as_float(p[j].y);
      acc.x = fmaf(v, bf2f(g[j].x), acc.x); acc.y = fmaf(v, bf2f(g[j].y), acc.y);
      acc.z = fmaf(v, bf2f(g[j].z), acc.z); acc.w = fmaf(v, bf2f(g[j].w), acc.w);
    }
  }
  for (; e < e1; ++e) {
    int2 p = ep[e];
    float v = __int_as_float(p.y);
    ushort4 g = srcv[(size_t)p.x * (NH / 4) + lane];
    acc.x = fmaf(v, bf2f(g.x), acc.x); acc.y = fmaf(v, bf2f(g.y), acc.y);
    acc.z = fmaf(v, bf2f(g.z), acc.z); acc.w = fmaf(v, bf2f(g.w), acc.w);
  }
  float4 b = ((const float4*)bias)[lane];
  ushort4 o;
  o.x = f2bf(fmaxf(acc.x + b.x, 0.f));
  o.y = f2bf(fmaxf(acc.y + b.y, 0.f));
  o.z = f2bf(fmaxf(acc.z + b.z, 0.f));
  o.w = f2bf(fmaxf(acc.w + b.w, 0.f));
  out[(size_t)row * (NH / 4) + lane] = o;
}

extern "C" __global__ __launch_bounds__(256) void k_spmm128(
    const int* __restrict__ rp, const int2* __restrict__ ep,
    const unsigned short* __restrict__ src, const float* __restrict__ bias,
    float2* __restrict__ out) {
  int row = blockIdx.x * 4 + (threadIdx.x >> 6);
  int lane = threadIdx.x & 63;
  if (row >= NN) return;
  int e0 = __builtin_amdgcn_readfirstlane(rp[row]);
  int e1 = __builtin_amdgcn_readfirstlane(rp[row + 1]);
  const ushort2* srcv = (const ushort2*)src;
  float2 acc = {0.f, 0.f};
  int e = e0;
  for (; e + 8 <= e1; e += 8) {
    int2 p[8]; ushort2 g[8];
#pragma unroll
    for (int j = 0; j < 8; ++j) p[j] = ep[e + j];
#pragma unroll
    for (int j = 0; j < 8; ++j) g[j] = srcv[(size_t)p[j].x * (NL / 2) + lane];
#pragma unroll
    for (int j = 0; j < 8; ++j) {
      float v = __int_as_float(p[j].y);
      acc.x = fmaf(v, bf2f(g[j].x), acc.x); acc.y = fmaf(v, bf2f(g[j].y), acc.y);
    }
  }
  for (; e + 4 <= e1; e += 4) {
    int2 p[4]; ushort2 g[4];
#pragma unroll
    for (int j = 0; j < 4; ++j) p[j] = ep[e + j];
#pragma unroll
    for (int j = 0; j < 4; ++j) g[j] = srcv[(size_t)p[j].x * (NL / 2) + lane];
#pragma unroll
    for (int j = 0; j < 4; ++j) {
      float v = __int_as_float(p[j].y);
      acc.x = fmaf(v, bf2f(g[j].x), acc.x); acc.y = fmaf(v, bf2f(g[j].y), acc.y);
    }
  }
  for (; e < e1; ++e) {
    int2 p = ep[e];
    float v = __int_as_float(p.y);
    ushort2 g = srcv[(size_t)p.x * (NL / 2) + lane];
    acc.x = fmaf(v, bf2f(g.x), acc.x); acc.y = fmaf(v, bf2f(g.y), acc.y);
  }
  float2 b = ((const float2*)bias)[lane];
  float2 o;
  o.x = fmaxf(acc.x + b.x, 0.f);
  o.y = fmaxf(acc.y + b.y, 0.f);
  out[(size_t)row * (NL / 2) + lane] = o;
}

// ---------------- launch ----------------
extern "C" void kernel_launch(void* const* d_in, const int* in_sizes, int n_in,
                              void* d_out, int out_size, void* d_ws, size_t ws_size,
                              hipStream_t stream) {
  const float* x   = (const float*)d_in[0];
  const int* erow  = (const int*)d_in[1];
  const int* ecol  = (const int*)d_in[2];
  const float* ev  = (const float*)d_in[3];
  const float* W1  = (const float*)d_in[4];
  const float* b1  = (const float*)d_in[5];
  const float* W2  = (const float*)d_in[6];
  const float* b2  = (const float*)d_in[7];

  char* ws = (char*)d_ws;
  unsigned short* xwb = (unsigned short*)(ws + 0);           // 25,600,000 (x@W1 bf16)
  unsigned short* hbf = (unsigned short*)(ws + 25600000);    // 25,600,000 (h bf16)
  unsigned short* hwb = (unsigned short*)(ws + 51200000);    // 12,800,000 (h@W2 bf16)
  unsigned short* w1t = (unsigned short*)(ws + 64000000);    // 262,144
  unsigned short* w2t = (unsigned short*)(ws + 64262144);    // 65,536
  int* rp    = (int*)(ws + 64327680);                        // 200,704
  int* cur   = (int*)(ws + 64528384);                        // 200,704
  int* cnt   = (int*)(ws + 64729088);                        // 200,704
  int* bsum  = (int*)(ws + 64929792);                        // 1,024
  int* bpre  = (int*)(ws + 64930816);                        // 1,024
  int2* ep   = (int2*)(ws + 64931840);                       // 6,400,000

  // CSR build
  hipMemsetAsync(cnt, 0, NN * sizeof(int), stream);
  k_hist<<<NE / 256, 256, 0, stream>>>(erow, cnt, NE);
  k_blocksum<<<NB, 256, 0, stream>>>(cnt, bsum, NN);
  k_scansums<<<1, 256, 0, stream>>>(bsum, bpre, rp, NB, NN);
  k_scanfin<<<NB, 256, 0, stream>>>(cnt, bpre, rp, cur, NN);
  k_scatter<<<NE / 256, 256, 0, stream>>>(erow, ecol, ev, cur, ep, NE);

  // layer 1
  k_transcast<<<NF, NH, 0, stream>>>(W1, w1t, NF, NH);
  k_gemm1<<<(NN + 63) / 64, 256, 0, stream>>>(x, w1t, xwb);
  k_spmm256<<<NN / 4, 256, 0, stream>>>(rp, ep, xwb, b1, (ushort4*)hbf);

  // layer 2
  k_transcast<<<NH, NL, 0, stream>>>(W2, w2t, NH, NL);
  k_gemm2<<<(NN + 63) / 64, 256, 0, stream>>>(hbf, w2t, hwb);
  k_spmm128<<<NN / 4, 256, 0, stream>>>(rp, ep, hwb, b2, (float2*)d_out);
}

// Round 11
// 380.614 us; speedup vs baseline: 1.2720x; 1.0042x over previous
//
#include <hip/hip_runtime.h>
#include <hip/hip_bf16.h>

// GCN encoder: z = relu(A @ relu(A @ (x@W1) + b1) @ W2 + b2)
// R16: fuse gemm2 INTO spmm256 (k_spmm256g2). Across R6-R15, total = gemm1 +
// ~317us constant; gemm1 is pinned at ~65us by a latency floor 6 structures
// couldn't move, so attack the invisible 317: spmm256 already has each h-row
// in registers -> stage 16 rows in LDS (bf16, identical to old hbf numerics),
// one barrier, then a 16x128 K=256 MFMA epilogue (W2 amortized 16 rows/read)
// writes hwb directly. Deletes gemm2 kernel+launch, the 51MB hbf round-trip,
// and one transcast launch (W1+W2 transcast merged). gemm1 = R15 unchanged
// (single-pass A, 52MB FETCH, 65us proven).

typedef __attribute__((ext_vector_type(8))) short bf16x8;
typedef __attribute__((ext_vector_type(4))) float f32x4;

#define NN 50000
#define NE 800000
#define NF 512
#define NH 256
#define NL 128
#define NB ((NN + 255) / 256)

static __device__ __forceinline__ unsigned short f2bf(float f) {
  union { float f; unsigned int u; } v; v.f = f;
  unsigned int r = v.u + 0x7fffu + ((v.u >> 16) & 1u);   // RNE
  return (unsigned short)(r >> 16);
}
static __device__ __forceinline__ float bf2f(unsigned short u) {
  union { unsigned int u; float f; } v; v.u = (unsigned int)u << 16;
  return v.f;
}

// HW packed f32->bf16 (RNE), 2 elems / instruction (no builtin on gfx950).
static __device__ __forceinline__ unsigned int pkbf(float lo, float hi) {
  unsigned int r;
  asm("v_cvt_pk_bf16_f32 %0, %1, %2" : "=v"(r) : "v"(lo), "v"(hi));
  return r;
}
static __device__ __forceinline__ uint4 pk8(float4 a, float4 b) {
  uint4 o;
  o.x = pkbf(a.x, a.y); o.y = pkbf(a.z, a.w);
  o.z = pkbf(b.x, b.y); o.w = pkbf(b.z, b.w);
  return o;
}

// async global->LDS, 16B/lane; LDS dest must be wave-uniform base + lane*16.
static __device__ __forceinline__ void gll16(const void* g, void* l) {
  __builtin_amdgcn_global_load_lds(
      (const __attribute__((address_space(1))) void*)g,
      (__attribute__((address_space(3))) void*)l, 16, 0, 0);
}

// ---------------- CSR build ----------------
extern "C" __global__ void k_hist(const int* __restrict__ rows, int* __restrict__ counts, int n) {
  int i = blockIdx.x * 256 + threadIdx.x;
  if (i < n) atomicAdd(&counts[rows[i]], 1);
}

extern "C" __global__ __launch_bounds__(256) void k_blocksum(
    const int* __restrict__ counts, int* __restrict__ bsum, int n) {
  __shared__ int s[256];
  int t = threadIdx.x;
  int i = blockIdx.x * 256 + t;
  s[t] = (i < n) ? counts[i] : 0;
  __syncthreads();
  for (int off = 128; off > 0; off >>= 1) {
    if (t < off) s[t] += s[t + off];
    __syncthreads();
  }
  if (t == 0) bsum[blockIdx.x] = s[0];
}

extern "C" __global__ __launch_bounds__(256) void k_scansums(
    const int* __restrict__ bsum, int* __restrict__ bpre, int* __restrict__ rp, int nb, int n) {
  __shared__ int s[256];
  int t = threadIdx.x;
  int v = (t < nb) ? bsum[t] : 0;
  s[t] = v;
  __syncthreads();
  for (int off = 1; off < 256; off <<= 1) {
    int u = (t >= off) ? s[t - off] : 0;
    __syncthreads();
    s[t] += u;
    __syncthreads();
  }
  if (t < nb) bpre[t] = s[t] - v;
  if (t == 255) rp[n] = s[255];
}

extern "C" __global__ __launch_bounds__(256) void k_scanfin(
    const int* __restrict__ counts, const int* __restrict__ bpre,
    int* __restrict__ rp, int* __restrict__ cur, int n) {
  __shared__ int s[256];
  int t = threadIdx.x;
  int i = blockIdx.x * 256 + t;
  int c = (i < n) ? counts[i] : 0;
  s[t] = c;
  __syncthreads();
  for (int off = 1; off < 256; off <<= 1) {
    int u = (t >= off) ? s[t - off] : 0;
    __syncthreads();
    s[t] += u;
    __syncthreads();
  }
  if (i < n) {
    int e = bpre[blockIdx.x] + s[t] - c;
    rp[i] = e;
    cur[i] = e;
  }
}

extern "C" __global__ void k_scatter(const int* __restrict__ rows, const int* __restrict__ cols,
    const float* __restrict__ vals, int* __restrict__ cur, int2* __restrict__ ep, int n) {
  int i = blockIdx.x * 256 + threadIdx.x;
  if (i < n) {
    int p = atomicAdd(&cur[rows[i]], 1);
    int2 e; e.x = cols[i]; e.y = __float_as_int(vals[i]);
    ep[p] = e;
  }
}

// ---------------- merged weight transpose-cast: W1 and W2 in one launch ----------------
extern "C" __global__ void k_transcast2(const float* __restrict__ W1, unsigned short* __restrict__ w1t,
                                        const float* __restrict__ W2, unsigned short* __restrict__ w2t) {
  int b = blockIdx.x, n = threadIdx.x;
  if (b < NF) {
    // W1 [NF][NH] -> w1t [NH][NF]
    w1t[(size_t)n * NF + b] = f2bf(W1[(size_t)b * NH + n]);
  } else {
    int k = b - NF;   // [0, NH)
    if (n < NL) w2t[(size_t)n * NH + k] = f2bf(W2[(size_t)k * NL + n]);
  }
}

// ---------------- GEMM1 (R15, unchanged): C[NN][256] = x * W1T^T, bf16 out ----------------
// BM=64 (4 waves x 16 rows), all 256 cols per block via 8 B-panels of 32.
extern "C" __global__ __launch_bounds__(256, 2) void k_gemm1(
    const float* __restrict__ A, const unsigned short* __restrict__ BT,
    unsigned short* __restrict__ C) {
  __shared__ __align__(16) unsigned short sB[2][32 * 512];   // 2 x 32KB: [col][K]
  int tid = threadIdx.x;
  int lane = tid & 63, wid = tid >> 6;
  int l15 = lane & 15, lq = lane >> 4;
  int bm = blockIdx.x * 64;

  auto issueB = [&](int q, int b) {
#pragma unroll
    for (int j = 0; j < 8; ++j) {
      int u = tid + 256 * j;
      int c = u >> 6, cu = u & 63;
      int g = cu ^ (c & 7);
      gll16(BT + (size_t)(q * 32 + c) * NF + g * 8, &sB[b][u * 8]);
    }
  };

  int arow = bm + wid * 16 + l15; if (arow >= NN) arow = NN - 1;
  const float* ap = A + (size_t)arow * NF + lq * 8;

  issueB(0, 0);
  float4 apf[4][2];
#pragma unroll
  for (int p = 0; p < 4; ++p) {
    apf[p][0] = *(const float4*)(ap + p * 32);
    apf[p][1] = *(const float4*)(ap + p * 32 + 4);
  }
  __syncthreads();          // B0 resident
  issueB(1, 1);

  bf16x8 abf[16];
  f32x4 acc[16];
#pragma unroll
  for (int i = 0; i < 16; ++i) acc[i] = (f32x4){0.f, 0.f, 0.f, 0.f};

#pragma unroll
  for (int p = 0; p < 16; ++p) {
    bf16x8 bfr[2];
#pragma unroll
    for (int nt = 0; nt < 2; ++nt) {
      int c = nt * 16 + l15;
      int u = (p * 4 + lq) ^ (c & 7);
      bfr[nt] = *(const bf16x8*)(&sB[0][c * 512 + u * 8]);
    }
    union { uint4 u; bf16x8 v; } cv;
    cv.u = pk8(apf[p & 3][0], apf[p & 3][1]);
    abf[p] = cv.v;
    if (p < 12) {
      apf[p & 3][0] = *(const float4*)(ap + (p + 4) * 32);
      apf[p & 3][1] = *(const float4*)(ap + (p + 4) * 32 + 4);
    }
#pragma unroll
    for (int nt = 0; nt < 2; ++nt)
      acc[nt] = __builtin_amdgcn_mfma_f32_16x16x32_bf16(abf[p], bfr[nt], acc[nt], 0, 0, 0);
  }
  __syncthreads();

#pragma unroll
  for (int q = 1; q < 8; ++q) {
    if (q < 7) issueB(q + 1, (q + 1) & 1);
#pragma unroll
    for (int p = 0; p < 16; ++p) {
      bf16x8 bfr[2];
#pragma unroll
      for (int nt = 0; nt < 2; ++nt) {
        int c = nt * 16 + l15;
        int u = (p * 4 + lq) ^ (c & 7);
        bfr[nt] = *(const bf16x8*)(&sB[q & 1][c * 512 + u * 8]);
      }
#pragma unroll
      for (int nt = 0; nt < 2; ++nt)
        acc[q * 2 + nt] = __builtin_amdgcn_mfma_f32_16x16x32_bf16(abf[p], bfr[nt], acc[q * 2 + nt], 0, 0, 0);
    }
    if (q < 7) __syncthreads();
  }

#pragma unroll
  for (int t = 0; t < 16; ++t) {
#pragma unroll
    for (int r = 0; r < 4; ++r) {
      int gr = bm + wid * 16 + lq * 4 + r;
      if (gr < NN) {
        int gc = t * 16 + l15;
        C[(size_t)gr * NH + gc] = f2bf(acc[t][r]);
      }
    }
  }
}

// ---------------- fused SpMM(256) + bias + relu + GEMM2: hwb = relu(A@xwb + b1) @ W2 ----------------
// Block = 16 rows (50000 = 3125*16 exact). Wave w gathers rows {w, w+4, w+8,
// w+12} into sh[16][264] (bf16 == old hbf numerics; pad -> 2-way-free banks).
// One barrier, then 16x128 K=256 MFMA epilogue: wave w owns col-tiles 2w,2w+1;
// B from L2-hot w2t (amortized 16 rows/read). Writes hwb only.
extern "C" __global__ __launch_bounds__(256) void k_spmm256g2(
    const int* __restrict__ rp, const int2* __restrict__ ep,
    const unsigned short* __restrict__ src, const float* __restrict__ bias,
    const unsigned short* __restrict__ w2t, unsigned short* __restrict__ hwb) {
  __shared__ __align__(16) unsigned short sh[16][264];
  int base = blockIdx.x * 16;
  int lane = threadIdx.x & 63, w = threadIdx.x >> 6;
  const ushort4* srcv = (const ushort4*)src;
  float4 b = ((const float4*)bias)[lane];

#pragma unroll
  for (int i = 0; i < 4; ++i) {
    int rl = w + i * 4;                 // local row 0..15
    int row = base + rl;                // always < NN
    int e0 = __builtin_amdgcn_readfirstlane(rp[row]);
    int e1 = __builtin_amdgcn_readfirstlane(rp[row + 1]);
    float4 acc = {0.f, 0.f, 0.f, 0.f};
    int e = e0;
    for (; e + 8 <= e1; e += 8) {
      int2 p[8]; ushort4 g[8];
#pragma unroll
      for (int j = 0; j < 8; ++j) p[j] = ep[e + j];
#pragma unroll
      for (int j = 0; j < 8; ++j) g[j] = srcv[(size_t)p[j].x * (NH / 4) + lane];
#pragma unroll
      for (int j = 0; j < 8; ++j) {
        float v = __int_as_float(p[j].y);
        acc.x = fmaf(v, bf2f(g[j].x), acc.x); acc.y = fmaf(v, bf2f(g[j].y), acc.y);
        acc.z = fmaf(v, bf2f(g[j].z), acc.z); acc.w = fmaf(v, bf2f(g[j].w), acc.w);
      }
    }
    for (; e + 4 <= e1; e += 4) {
      int2 p[4]; ushort4 g[4];
#pragma unroll
      for (int j = 0; j < 4; ++j) p[j] = ep[e + j];
#pragma unroll
      for (int j = 0; j < 4; ++j) g[j] = srcv[(size_t)p[j].x * (NH / 4) + lane];
#pragma unroll
      for (int j = 0; j < 4; ++j) {
        float v = __int_as_float(p[j].y);
        acc.x = fmaf(v, bf2f(g[j].x), acc.x); acc.y = fmaf(v, bf2f(g[j].y), acc.y);
        acc.z = fmaf(v, bf2f(g[j].z), acc.z); acc.w = fmaf(v, bf2f(g[j].w), acc.w);
      }
    }
    for (; e < e1; ++e) {
      int2 p = ep[e];
      float v = __int_as_float(p.y);
      ushort4 g = srcv[(size_t)p.x * (NH / 4) + lane];
      acc.x = fmaf(v, bf2f(g.x), acc.x); acc.y = fmaf(v, bf2f(g.y), acc.y);
      acc.z = fmaf(v, bf2f(g.z), acc.z); acc.w = fmaf(v, bf2f(g.w), acc.w);
    }
    ushort4 o;
    o.x = f2bf(fmaxf(acc.x + b.x, 0.f));
    o.y = f2bf(fmaxf(acc.y + b.y, 0.f));
    o.z = f2bf(fmaxf(acc.z + b.z, 0.f));
    o.w = f2bf(fmaxf(acc.w + b.w, 0.f));
    *(ushort4*)(&sh[rl][lane * 4]) = o;
  }
  __syncthreads();

  // ---- MFMA epilogue: hwb[base..base+15][0..127] = sh @ w2t^T
  int l15 = lane & 15, lq = lane >> 4;
  f32x4 acc2[2];
  acc2[0] = (f32x4){0.f, 0.f, 0.f, 0.f};
  acc2[1] = (f32x4){0.f, 0.f, 0.f, 0.f};
  const unsigned short* bp[2];
#pragma unroll
  for (int t = 0; t < 2; ++t)
    bp[t] = w2t + (size_t)(w * 32 + t * 16 + l15) * NH + lq * 8;
#pragma unroll
  for (int ks = 0; ks < 8; ++ks) {
    bf16x8 af = *(const bf16x8*)(&sh[l15][ks * 32 + lq * 8]);
#pragma unroll
    for (int t = 0; t < 2; ++t) {
      bf16x8 bfr = *(const bf16x8*)(bp[t] + ks * 32);
      acc2[t] = __builtin_amdgcn_mfma_f32_16x16x32_bf16(af, bfr, acc2[t], 0, 0, 0);
    }
  }
#pragma unroll
  for (int t = 0; t < 2; ++t) {
#pragma unroll
    for (int r = 0; r < 4; ++r) {
      int gr = base + lq * 4 + r;
      int gc = w * 32 + t * 16 + l15;
      hwb[(size_t)gr * NL + gc] = f2bf(acc2[t][r]);
    }
  }
}

// ---------------- SpMM(128) (CSR row-gather), bf16 src, fused bias+relu ----------------
extern "C" __global__ __launch_bounds__(256) void k_spmm128(
    const int* __restrict__ rp, const int2* __restrict__ ep,
    const unsigned short* __restrict__ src, const float* __restrict__ bias,
    float2* __restrict__ out) {
  int row = blockIdx.x * 4 + (threadIdx.x >> 6);
  int lane = threadIdx.x & 63;
  if (row >= NN) return;
  int e0 = __builtin_amdgcn_readfirstlane(rp[row]);
  int e1 = __builtin_amdgcn_readfirstlane(rp[row + 1]);
  const ushort2* srcv = (const ushort2*)src;
  float2 acc = {0.f, 0.f};
  int e = e0;
  for (; e + 8 <= e1; e += 8) {
    int2 p[8]; ushort2 g[8];
#pragma unroll
    for (int j = 0; j < 8; ++j) p[j] = ep[e + j];
#pragma unroll
    for (int j = 0; j < 8; ++j) g[j] = srcv[(size_t)p[j].x * (NL / 2) + lane];
#pragma unroll
    for (int j = 0; j < 8; ++j) {
      float v = __int_as_float(p[j].y);
      acc.x = fmaf(v, bf2f(g[j].x), acc.x); acc.y = fmaf(v, bf2f(g[j].y), acc.y);
    }
  }
  for (; e + 4 <= e1; e += 4) {
    int2 p[4]; ushort2 g[4];
#pragma unroll
    for (int j = 0; j < 4; ++j) p[j] = ep[e + j];
#pragma unroll
    for (int j = 0; j < 4; ++j) g[j] = srcv[(size_t)p[j].x * (NL / 2) + lane];
#pragma unroll
    for (int j = 0; j < 4; ++j) {
      float v = __int_as_float(p[j].y);
      acc.x = fmaf(v, bf2f(g[j].x), acc.x); acc.y = fmaf(v, bf2f(g[j].y), acc.y);
    }
  }
  for (; e < e1; ++e) {
    int2 p = ep[e];
    float v = __int_as_float(p.y);
    ushort2 g = srcv[(size_t)p.x * (NL / 2) + lane];
    acc.x = fmaf(v, bf2f(g.x), acc.x); acc.y = fmaf(v, bf2f(g.y), acc.y);
  }
  float2 b = ((const float2*)bias)[lane];
  float2 o;
  o.x = fmaxf(acc.x + b.x, 0.f);
  o.y = fmaxf(acc.y + b.y, 0.f);
  out[(size_t)row * (NL / 2) + lane] = o;
}

// ---------------- launch ----------------
extern "C" void kernel_launch(void* const* d_in, const int* in_sizes, int n_in,
                              void* d_out, int out_size, void* d_ws, size_t ws_size,
                              hipStream_t stream) {
  const float* x   = (const float*)d_in[0];
  const int* erow  = (const int*)d_in[1];
  const int* ecol  = (const int*)d_in[2];
  const float* ev  = (const float*)d_in[3];
  const float* W1  = (const float*)d_in[4];
  const float* b1  = (const float*)d_in[5];
  const float* W2  = (const float*)d_in[6];
  const float* b2  = (const float*)d_in[7];

  char* ws = (char*)d_ws;
  unsigned short* xwb = (unsigned short*)(ws + 0);           // 25,600,000 (x@W1 bf16)
  unsigned short* hwb = (unsigned short*)(ws + 51200000);    // 12,800,000 (h@W2 bf16)
  unsigned short* w1t = (unsigned short*)(ws + 64000000);    // 262,144
  unsigned short* w2t = (unsigned short*)(ws + 64262144);    // 65,536
  int* rp    = (int*)(ws + 64327680);                        // 200,704
  int* cur   = (int*)(ws + 64528384);                        // 200,704
  int* cnt   = (int*)(ws + 64729088);                        // 200,704
  int* bsum  = (int*)(ws + 64929792);                        // 1,024
  int* bpre  = (int*)(ws + 64930816);                        // 1,024
  int2* ep   = (int2*)(ws + 64931840);                       // 6,400,000

  // CSR build
  hipMemsetAsync(cnt, 0, NN * sizeof(int), stream);
  k_hist<<<NE / 256, 256, 0, stream>>>(erow, cnt, NE);
  k_blocksum<<<NB, 256, 0, stream>>>(cnt, bsum, NN);
  k_scansums<<<1, 256, 0, stream>>>(bsum, bpre, rp, NB, NN);
  k_scanfin<<<NB, 256, 0, stream>>>(cnt, bpre, rp, cur, NN);
  k_scatter<<<NE / 256, 256, 0, stream>>>(erow, ecol, ev, cur, ep, NE);

  // weights (merged)
  k_transcast2<<<NF + NH, NH, 0, stream>>>(W1, w1t, W2, w2t);

  // layer 1 GEMM
  k_gemm1<<<(NN + 63) / 64, 256, 0, stream>>>(x, w1t, xwb);

  // fused: h = relu(A@xwb + b1); hwb = h@W2
  k_spmm256g2<<<NN / 16, 256, 0, stream>>>(rp, ep, xwb, b1, w2t, hwb);

  // layer 2 SpMM + bias + relu -> out
  k_spmm128<<<NN / 4, 256, 0, stream>>>(rp, ep, hwb, b2, (float2*)d_out);
}